// Round 1
// baseline (141.283 us; speedup 1.0000x reference)
//
#include <hip/hip_runtime.h>

#define SEQ 2048
#define NBATCH 8
#define NROWS (NBATCH*SEQ)   // 16384
#define DMODEL 1024
#define DHEAD 64
#define ATT_SCALE 0.03125f   // 1/sqrt(1024)

typedef __attribute__((ext_vector_type(8))) short bf16x8;
typedef __attribute__((ext_vector_type(4))) float f32x4;
typedef __attribute__((ext_vector_type(4))) unsigned int u32x4;
typedef __attribute__((ext_vector_type(4))) unsigned short u16x4;
typedef __attribute__((ext_vector_type(4))) float fl4;

#define MFMA16(a,b,c) __builtin_amdgcn_mfma_f32_16x16x32_bf16((a),(b),(c),0,0,0)

__device__ __forceinline__ unsigned short f2bf(float f) {
    union { float f; unsigned int u; } v; v.f = f;
    unsigned int u = v.u;
    unsigned int r = u + 0x7fffu + ((u >> 16) & 1u);
    return (unsigned short)(r >> 16);
}

// ---------------- kernel 0: convert weights to bf16 ----------------
__global__ __launch_bounds__(256) void k_cvt(
    const float* __restrict__ Wq, const float* __restrict__ Wk,
    const float* __restrict__ Wv, const float* __restrict__ Wo,
    unsigned short* __restrict__ Wb,    // [192][1024] (Wq;Wk;Wv)
    unsigned short* __restrict__ Wob)   // [1024][64]
{
    int i4 = blockIdx.x * 256 + threadIdx.x;   // 0..65535 float4s
    const int W1 = 16384;                      // float4 per 64*1024
    const float* src; unsigned short* dst; int off;
    if (i4 < 3 * W1) {
        int which = i4 / W1;
        off = i4 - which * W1;
        src = (which == 0) ? Wq : (which == 1) ? Wk : Wv;
        dst = Wb + (size_t)which * 65536;
    } else {
        off = i4 - 3 * W1; src = Wo; dst = Wob;
    }
    fl4 v = reinterpret_cast<const fl4*>(src)[off];
    u16x4 o;
    o[0] = f2bf(v[0]); o[1] = f2bf(v[1]); o[2] = f2bf(v[2]); o[3] = f2bf(v[3]);
    reinterpret_cast<u16x4*>(dst)[off] = o;
}

// ---------------- kernel A: QKV projection (+ V transpose) ----------------
// x[16384][1024] fp32 * Wb[192][1024] bf16 -> Qb,Kb [16384][64] bf16, Vt [8][64][2048] bf16
__global__ __launch_bounds__(256) void k_qkv(
    const float* __restrict__ x,
    const unsigned short* __restrict__ Wb,
    unsigned short* __restrict__ Qb,
    unsigned short* __restrict__ Kb,
    unsigned short* __restrict__ Vt)
{
    __shared__ __align__(16) unsigned short smem[64*64 + 192*64];
    unsigned short* Xl = smem;          // [64][64] bf16, 16B-chunk XOR swizzled
    unsigned short* Wl = smem + 4096;   // [192][64] bf16, swizzled

    int tid = threadIdx.x;
    int wave = tid >> 6, lane = tid & 63, g = lane >> 4, lr = lane & 15;
    int mbase = blockIdx.x * 64;

    f32x4 acc[12];
#pragma unroll
    for (int f = 0; f < 12; ++f) acc[f] = (f32x4){0.f, 0.f, 0.f, 0.f};

    for (int ks = 0; ks < 16; ++ks) {
        int kbase = ks * 64;
        // stage x tile [64][64] fp32 -> bf16 (4 passes x 256 thr x 4 floats)
#pragma unroll
        for (int p = 0; p < 4; ++p) {
            int idx = p * 256 + tid;
            int row = idx >> 4, c4 = idx & 15;
            fl4 v = *reinterpret_cast<const fl4*>(
                &x[(size_t)(mbase + row) * DMODEL + kbase + c4 * 4]);
            u16x4 o;
            o[0] = f2bf(v[0]); o[1] = f2bf(v[1]); o[2] = f2bf(v[2]); o[3] = f2bf(v[3]);
            int ch = (c4 >> 1) ^ (row & 7);
            *reinterpret_cast<u16x4*>(&Xl[row * 64 + ch * 8 + (c4 & 1) * 4]) = o;
        }
        // stage W slice [192][64] bf16 (6 passes x 256 thr x 8 bf16)
#pragma unroll
        for (int p = 0; p < 6; ++p) {
            int idx = p * 256 + tid;
            int row = idx >> 3, c = idx & 7;
            u32x4 v = *reinterpret_cast<const u32x4*>(
                &Wb[(size_t)row * DMODEL + kbase + c * 8]);
            int ch = c ^ (row & 7);
            *reinterpret_cast<u32x4*>(&Wl[row * 64 + ch * 8]) = v;
        }
        __syncthreads();
#pragma unroll
        for (int kc = 0; kc < 2; ++kc) {
            int arow = wave * 16 + lr;
            int ca = (kc * 4 + g) ^ (arow & 7);
            bf16x8 aX = *reinterpret_cast<const bf16x8*>(&Xl[arow * 64 + ca * 8]);
#pragma unroll
            for (int f = 0; f < 12; ++f) {
                int brow = f * 16 + lr;
                int cb = (kc * 4 + g) ^ (brow & 7);
                bf16x8 bW = *reinterpret_cast<const bf16x8*>(&Wl[brow * 64 + cb * 8]);
                acc[f] = MFMA16(aX, bW, acc[f]);
            }
        }
        __syncthreads();
    }

    // ---- write Q, K (D-layout: row=(lane>>4)*4+r, col=lane&15) ----
    int mrow = mbase + wave * 16 + g * 4;
#pragma unroll
    for (int f = 0; f < 8; ++f) {
        int col = f * 16 + lr;
#pragma unroll
        for (int r = 0; r < 4; ++r) {
            unsigned short bv = f2bf(acc[f][r]);
            if (f < 4) Qb[(size_t)(mrow + r) * DHEAD + col] = bv;
            else       Kb[(size_t)(mrow + r) * DHEAD + col - 64] = bv;
        }
    }
    // ---- V: repack via LDS, store transposed Vt[b][h][s] ----
    unsigned short* tmp = smem;  // [64][72]
#pragma unroll
    for (int f = 8; f < 12; ++f) {
        int h = (f - 8) * 16 + lr;
#pragma unroll
        for (int r = 0; r < 4; ++r)
            tmp[(wave * 16 + g * 4 + r) * 72 + h] = f2bf(acc[f][r]);
    }
    __syncthreads();
    int b = mbase >> 11, sbase = mbase & 2047;
    int h = tid >> 2, sc = tid & 3;
    u32x4 o0, o1;
#pragma unroll
    for (int j = 0; j < 4; ++j) {
        o0[j] = (unsigned int)tmp[(sc * 16 + 2 * j) * 72 + h] |
                ((unsigned int)tmp[(sc * 16 + 2 * j + 1) * 72 + h] << 16);
        o1[j] = (unsigned int)tmp[(sc * 16 + 8 + 2 * j) * 72 + h] |
                ((unsigned int)tmp[(sc * 16 + 9 + 2 * j) * 72 + h] << 16);
    }
    size_t off = ((size_t)(b * 64 + h)) * SEQ + sbase + sc * 16;
    *reinterpret_cast<u32x4*>(&Vt[off]) = o0;
    *reinterpret_cast<u32x4*>(&Vt[off + 8]) = o1;
}

// ---------------- kernel B: causal flash attention ----------------
// Qb,Kb [16384][64] bf16, Vt [8][64][2048] bf16 -> Ob [16384][64] bf16
__global__ __launch_bounds__(256) void k_attn(
    const unsigned short* __restrict__ Qb,
    const unsigned short* __restrict__ Kb,
    const unsigned short* __restrict__ Vt,
    unsigned short* __restrict__ Ob)
{
    __shared__ __align__(16) unsigned short Kl[64 * 64];
    __shared__ __align__(16) unsigned short Vl[64 * 64];  // [d][kv]
    __shared__ __align__(16) unsigned short Pl[4 * 16 * 64];

    int tid = threadIdx.x;
    int wave = tid >> 6, lane = tid & 63, g = lane >> 4, lr = lane & 15;
    int qblock = blockIdx.x, b = blockIdx.y;
    int qg = qblock * 64 + wave * 16;
    size_t qrowbase = (size_t)(b * SEQ + qg);

    bf16x8 aq[2];
#pragma unroll
    for (int kc = 0; kc < 2; ++kc)
        aq[kc] = *reinterpret_cast<const bf16x8*>(
            &Qb[(qrowbase + lr) * DHEAD + kc * 32 + g * 8]);

    float m_run[4], l_run[4];
    f32x4 of[4];
#pragma unroll
    for (int r = 0; r < 4; ++r) { m_run[r] = -1e30f; l_run[r] = 0.f; }
#pragma unroll
    for (int f = 0; f < 4; ++f) of[f] = (f32x4){0.f, 0.f, 0.f, 0.f};

    int ntiles = qblock + 1;
    for (int t = 0; t < ntiles; ++t) {
        int kvb = t * 64;
        // stage K [kv][d] and V^T [d][kv], both swizzled
#pragma unroll
        for (int p = 0; p < 2; ++p) {
            int idx = p * 256 + tid;
            int row = idx >> 3, c = idx & 7;
            int ch = c ^ (row & 7);
            u32x4 kv = *reinterpret_cast<const u32x4*>(
                &Kb[((size_t)(b * SEQ + kvb + row)) * DHEAD + c * 8]);
            *reinterpret_cast<u32x4*>(&Kl[row * 64 + ch * 8]) = kv;
            u32x4 vv = *reinterpret_cast<const u32x4*>(
                &Vt[((size_t)(b * 64 + row)) * SEQ + kvb + c * 8]);
            *reinterpret_cast<u32x4*>(&Vl[row * 64 + ch * 8]) = vv;
        }
        __syncthreads();

        // S = Q K^T
        f32x4 s[4];
#pragma unroll
        for (int f = 0; f < 4; ++f) s[f] = (f32x4){0.f, 0.f, 0.f, 0.f};
#pragma unroll
        for (int kc = 0; kc < 2; ++kc) {
#pragma unroll
            for (int f = 0; f < 4; ++f) {
                int brow = f * 16 + lr;
                int cb = (kc * 4 + g) ^ (brow & 7);
                bf16x8 bk = *reinterpret_cast<const bf16x8*>(&Kl[brow * 64 + cb * 8]);
                s[f] = MFMA16(aq[kc], bk, s[f]);
            }
        }
        // scale + causal mask
#pragma unroll
        for (int f = 0; f < 4; ++f) {
            int kvg = kvb + f * 16 + lr;
#pragma unroll
            for (int r = 0; r < 4; ++r) {
                float sv = s[f][r] * ATT_SCALE;
                int qr = qg + g * 4 + r;
                s[f][r] = (kvg > qr) ? -1e30f : sv;
            }
        }
        // online softmax (row r lives in the 16-lane group; reduce over cols)
#pragma unroll
        for (int r = 0; r < 4; ++r) {
            float mx = fmaxf(fmaxf(s[0][r], s[1][r]), fmaxf(s[2][r], s[3][r]));
            mx = fmaxf(mx, __shfl_xor(mx, 1));
            mx = fmaxf(mx, __shfl_xor(mx, 2));
            mx = fmaxf(mx, __shfl_xor(mx, 4));
            mx = fmaxf(mx, __shfl_xor(mx, 8));
            float nm = fmaxf(m_run[r], mx);
            float corr = __expf(m_run[r] - nm);
            m_run[r] = nm;
            float rs = 0.f;
#pragma unroll
            for (int f = 0; f < 4; ++f) {
                float p = __expf(s[f][r] - nm);
                s[f][r] = p;
                rs += p;
            }
            rs += __shfl_xor(rs, 1); rs += __shfl_xor(rs, 2);
            rs += __shfl_xor(rs, 4); rs += __shfl_xor(rs, 8);
            l_run[r] = l_run[r] * corr + rs;
#pragma unroll
            for (int fd = 0; fd < 4; ++fd) of[fd][r] *= corr;
        }
        // P -> per-wave LDS (swizzled), bf16
        int pb = wave * 1024;
#pragma unroll
        for (int f = 0; f < 4; ++f) {
#pragma unroll
            for (int r = 0; r < 4; ++r) {
                int row = g * 4 + r, col = f * 16 + lr;
                int ch = (col >> 3) ^ (row & 7);
                Pl[pb + row * 64 + ch * 8 + (col & 7)] = f2bf(s[f][r]);
            }
        }
        // O += P V
#pragma unroll
        for (int kc = 0; kc < 2; ++kc) {
            int cp = (kc * 4 + g) ^ (lr & 7);
            bf16x8 ap = *reinterpret_cast<const bf16x8*>(&Pl[pb + lr * 64 + cp * 8]);
#pragma unroll
            for (int fd = 0; fd < 4; ++fd) {
                int vrow = fd * 16 + lr;
                int cv = (kc * 4 + g) ^ (vrow & 7);
                bf16x8 bv = *reinterpret_cast<const bf16x8*>(&Vl[vrow * 64 + cv * 8]);
                of[fd] = MFMA16(ap, bv, of[fd]);
            }
        }
        __syncthreads();
    }
    // epilogue: normalize, store O bf16
#pragma unroll
    for (int fd = 0; fd < 4; ++fd) {
#pragma unroll
        for (int r = 0; r < 4; ++r) {
            Ob[(qrowbase + g * 4 + r) * DHEAD + fd * 16 + lr] =
                f2bf(of[fd][r] / l_run[r]);
        }
    }
}

// ---------------- kernel C: output projection ----------------
// Ob [16384][64] bf16 * Wob[1024][64] bf16 -> out [16384][1024] fp32
__global__ __launch_bounds__(256) void k_oproj(
    const unsigned short* __restrict__ Ob,
    const unsigned short* __restrict__ Wob,
    float* __restrict__ out)
{
    __shared__ __align__(16) unsigned short Wl[256 * 64];
    int tid = threadIdx.x;
    int wave = tid >> 6, lane = tid & 63, g = lane >> 4, lr = lane & 15;
    int mb = blockIdx.x * 64, nb = blockIdx.y * 256;

#pragma unroll
    for (int p = 0; p < 8; ++p) {
        int idx = p * 256 + tid;
        int row = idx >> 3, c = idx & 7;
        int ch = c ^ (row & 7);
        u32x4 v = *reinterpret_cast<const u32x4*>(
            &Wob[(size_t)(nb + row) * DHEAD + c * 8]);
        *reinterpret_cast<u32x4*>(&Wl[row * 64 + ch * 8]) = v;
    }
    __syncthreads();

    bf16x8 ao[2];
#pragma unroll
    for (int kc = 0; kc < 2; ++kc)
        ao[kc] = *reinterpret_cast<const bf16x8*>(
            &Ob[(size_t)(mb + wave * 16 + lr) * DHEAD + kc * 32 + g * 8]);

    f32x4 acc[16];
#pragma unroll
    for (int f = 0; f < 16; ++f) acc[f] = (f32x4){0.f, 0.f, 0.f, 0.f};
#pragma unroll
    for (int kc = 0; kc < 2; ++kc) {
#pragma unroll
        for (int f = 0; f < 16; ++f) {
            int brow = f * 16 + lr;
            int cb = (kc * 4 + g) ^ (brow & 7);
            bf16x8 bw = *reinterpret_cast<const bf16x8*>(&Wl[brow * 64 + cb * 8]);
            acc[f] = MFMA16(ao[kc], bw, acc[f]);
        }
    }
    int mrow = mb + wave * 16 + g * 4;
#pragma unroll
    for (int f = 0; f < 16; ++f) {
#pragma unroll
        for (int r = 0; r < 4; ++r)
            out[(size_t)(mrow + r) * DMODEL + nb + f * 16 + lr] = acc[f][r];
    }
}

extern "C" void kernel_launch(void* const* d_in, const int* in_sizes, int n_in,
                              void* d_out, int out_size, void* d_ws, size_t ws_size,
                              hipStream_t stream) {
    const float* x  = (const float*)d_in[0];
    const float* Wq = (const float*)d_in[1];
    const float* Wk = (const float*)d_in[2];
    const float* Wv = (const float*)d_in[3];
    const float* Wo = (const float*)d_in[4];
    float* out = (float*)d_out;

    unsigned short* Wb  = (unsigned short*)d_ws;   // 192*1024
    unsigned short* Wob = Wb + 196608;             // 1024*64
    unsigned short* Qb  = Wob + 65536;             // 16384*64
    unsigned short* Kb  = Qb + 1048576;
    unsigned short* Vt  = Kb + 1048576;            // [8][64][2048]
    unsigned short* Ob  = Vt + 1048576;

    k_cvt<<<256, 256, 0, stream>>>(Wq, Wk, Wv, Wo, Wb, Wob);
    k_qkv<<<256, 256, 0, stream>>>(x, Wb, Qb, Kb, Vt);
    k_attn<<<dim3(32, 8), 256, 0, stream>>>(Qb, Kb, Vt, Ob);
    k_oproj<<<dim3(256, 4), 256, 0, stream>>>(Ob, Wob, out);
}

// Round 2
// 102.782 us; speedup vs baseline: 1.3746x; 1.3746x over previous
//
#include <hip/hip_runtime.h>

#define SEQ 2048
#define DMODEL 1024
#define DHEAD 64
#define ATT_SCALE 0.03125f   // 1/sqrt(1024)

typedef __attribute__((ext_vector_type(8))) short bf16x8;
typedef __attribute__((ext_vector_type(4))) float f32x4;
typedef __attribute__((ext_vector_type(4))) unsigned int u32x4;
typedef __attribute__((ext_vector_type(4))) unsigned short u16x4;
typedef __attribute__((ext_vector_type(4))) float fl4;

#define MFMA16(a,b,c) __builtin_amdgcn_mfma_f32_16x16x32_bf16((a),(b),(c),0,0,0)
#define GLL16(g, l) __builtin_amdgcn_global_load_lds( \
    (const __attribute__((address_space(1))) void*)(g), \
    (__attribute__((address_space(3))) void*)(l), 16, 0, 0)

__device__ __forceinline__ unsigned short f2bf(float f) {
    union { float f; unsigned int u; } v; v.f = f;
    unsigned int u = v.u;
    unsigned int r = u + 0x7fffu + ((u >> 16) & 1u);
    return (unsigned short)(r >> 16);
}

// ---------------- kernel 0: convert weights to bf16 ----------------
__global__ __launch_bounds__(256) void k_cvt(
    const float* __restrict__ Wq, const float* __restrict__ Wk,
    const float* __restrict__ Wv, const float* __restrict__ Wo,
    unsigned short* __restrict__ Wb,    // [192][1024] (Wq;Wk;Wv)
    unsigned short* __restrict__ Wob)   // [1024][64]
{
    int i4 = blockIdx.x * 256 + threadIdx.x;   // 0..65535 float4s
    const int W1 = 16384;
    const float* src; unsigned short* dst; int off;
    if (i4 < 3 * W1) {
        int which = i4 / W1;
        off = i4 - which * W1;
        src = (which == 0) ? Wq : (which == 1) ? Wk : Wv;
        dst = Wb + (size_t)which * 65536;
    } else {
        off = i4 - 3 * W1; src = Wo; dst = Wob;
    }
    fl4 v = reinterpret_cast<const fl4*>(src)[off];
    u16x4 o;
    o[0] = f2bf(v[0]); o[1] = f2bf(v[1]); o[2] = f2bf(v[2]); o[3] = f2bf(v[3]);
    reinterpret_cast<u16x4*>(dst)[off] = o;
}

// ---------------- kernel A: QKV projection, async pipelined ----------------
// x[16384][1024] fp32 * Wb[192][1024] bf16 -> Qb,Kb [16384][64] bf16, Vt [8][64][2048] bf16
// LDS: X double-buf 2x16KB @0 (fp32, linear rows of 16 chunks, source pre-swizzled),
//      W double-buf 2x24KB @32768 (bf16, rows of 8 chunks, source pre-swizzled)
__global__ __launch_bounds__(256) void k_qkv(
    const float* __restrict__ x,
    const unsigned short* __restrict__ Wb,
    unsigned short* __restrict__ Qb,
    unsigned short* __restrict__ Kb,
    unsigned short* __restrict__ Vt)
{
    __shared__ __align__(16) char smem[81920];

    int tid = threadIdx.x;
    int wave = tid >> 6, lane = tid & 63, g = lane >> 4, lr = lane & 15;
    int mbase = blockIdx.x * 64;

    // staging source pointers (pre-swizzled: LDS slot (row,c) gets global chunk c^(row&7))
    const float* xsrc[4];
#pragma unroll
    for (int j = 0; j < 4; ++j) {
        int ci = (wave * 4 + j) * 64 + lane;
        int row = ci >> 4, c = ci & 15, cg = c ^ (row & 7);
        xsrc[j] = x + (size_t)(mbase + row) * DMODEL + cg * 4;
    }
    const unsigned short* wsrc[6];
#pragma unroll
    for (int j = 0; j < 6; ++j) {
        int ci = (wave * 6 + j) * 64 + lane;
        int row = ci >> 3, c = ci & 7, cg = c ^ (row & 7);
        wsrc[j] = Wb + (size_t)row * DMODEL + cg * 8;
    }

    f32x4 acc[12];
#pragma unroll
    for (int f = 0; f < 12; ++f) acc[f] = (f32x4){0.f, 0.f, 0.f, 0.f};

    // prologue: stage K-step 0 into buf 0
#pragma unroll
    for (int j = 0; j < 4; ++j) GLL16(xsrc[j], smem + (wave * 4 + j) * 1024);
#pragma unroll
    for (int j = 0; j < 6; ++j) GLL16(wsrc[j], smem + 32768 + (wave * 6 + j) * 1024);

    for (int ks = 0; ks < 16; ++ks) {
        int cur = ks & 1;
        if (ks < 15) {
            int nb = cur ^ 1;
#pragma unroll
            for (int j = 0; j < 4; ++j)
                GLL16(xsrc[j] + (ks + 1) * 64, smem + nb * 16384 + (wave * 4 + j) * 1024);
#pragma unroll
            for (int j = 0; j < 6; ++j)
                GLL16(wsrc[j] + (ks + 1) * 64, smem + 32768 + nb * 24576 + (wave * 6 + j) * 1024);
            asm volatile("s_waitcnt vmcnt(10)" ::: "memory");
        } else {
            asm volatile("s_waitcnt vmcnt(0)" ::: "memory");
        }
        __builtin_amdgcn_s_barrier();
        asm volatile("" ::: "memory");

        const float* Xf = (const float*)(smem + cur * 16384);
        const unsigned short* Wf = (const unsigned short*)(smem + 32768 + cur * 24576);
        int arow = wave * 16 + lr;   // (arow&7) == (lr&7)
#pragma unroll
        for (int kc = 0; kc < 2; ++kc) {
            int c0 = (kc * 8 + g * 2) ^ (lr & 7);
            int c1 = (kc * 8 + g * 2 + 1) ^ (lr & 7);
            fl4 xa = *(const fl4*)&Xf[arow * 64 + c0 * 4];
            fl4 xb = *(const fl4*)&Xf[arow * 64 + c1 * 4];
            bf16x8 a;
            a[0] = (short)f2bf(xa[0]); a[1] = (short)f2bf(xa[1]);
            a[2] = (short)f2bf(xa[2]); a[3] = (short)f2bf(xa[3]);
            a[4] = (short)f2bf(xb[0]); a[5] = (short)f2bf(xb[1]);
            a[6] = (short)f2bf(xb[2]); a[7] = (short)f2bf(xb[3]);
#pragma unroll
            for (int f = 0; f < 12; ++f) {
                int brow = f * 16 + lr;
                int cb = (kc * 4 + g) ^ (lr & 7);
                bf16x8 b = *(const bf16x8*)&Wf[brow * 64 + cb * 8];
                acc[f] = MFMA16(a, b, acc[f]);
            }
        }
        asm volatile("" ::: "memory");
        __builtin_amdgcn_s_barrier();
    }

    // ---- write Q, K (C/D layout: row=(lane>>4)*4+r, col=lane&15) ----
    int mrow = mbase + wave * 16 + g * 4;
#pragma unroll
    for (int f = 0; f < 8; ++f) {
        int col = f * 16 + lr;
#pragma unroll
        for (int r = 0; r < 4; ++r) {
            unsigned short bv = f2bf(acc[f][r]);
            if (f < 4) Qb[(size_t)(mrow + r) * DHEAD + col] = bv;
            else       Kb[(size_t)(mrow + r) * DHEAD + col - 64] = bv;
        }
    }
    // ---- V: repack via LDS, store transposed Vt[b][h][s] ----
    unsigned short* tmp = (unsigned short*)smem;  // [64][72]
#pragma unroll
    for (int f = 8; f < 12; ++f) {
        int h = (f - 8) * 16 + lr;
#pragma unroll
        for (int r = 0; r < 4; ++r)
            tmp[(wave * 16 + g * 4 + r) * 72 + h] = f2bf(acc[f][r]);
    }
    __syncthreads();
    int b = mbase >> 11, sbase = mbase & 2047;
    int h = tid >> 2, sc = tid & 3;
    u32x4 o0, o1;
#pragma unroll
    for (int j = 0; j < 4; ++j) {
        o0[j] = (unsigned int)tmp[(sc * 16 + 2 * j) * 72 + h] |
                ((unsigned int)tmp[(sc * 16 + 2 * j + 1) * 72 + h] << 16);
        o1[j] = (unsigned int)tmp[(sc * 16 + 8 + 2 * j) * 72 + h] |
                ((unsigned int)tmp[(sc * 16 + 9 + 2 * j) * 72 + h] << 16);
    }
    size_t off = ((size_t)(b * 64 + h)) * SEQ + sbase + sc * 16;
    *reinterpret_cast<u32x4*>(&Vt[off]) = o0;
    *reinterpret_cast<u32x4*>(&Vt[off + 8]) = o1;
}

// ---------------- kernel B: causal flash attention ----------------
// QBLK=32 (2 waves), KVBLK=64, 512 blocks (2/CU), heavy q-tiles first,
// double-buffered gload_lds K/V staging with counted vmcnt.
// LDS: K 2x8KB @0, V 2x8KB @16384, P 4KB @32768
__global__ __launch_bounds__(128) void k_attn(
    const unsigned short* __restrict__ Qb,
    const unsigned short* __restrict__ Kb,
    const unsigned short* __restrict__ Vt,
    unsigned short* __restrict__ Ob)
{
    __shared__ __align__(16) char smem[36864];

    int tid = threadIdx.x;
    int wave = tid >> 6, lane = tid & 63, g = lane >> 4, lr = lane & 15;
    int qt = 63 - blockIdx.x;          // heavy tiles dispatched first
    int b = blockIdx.y;
    int nt = qt / 2 + 1;               // kv tiles of 64 covering rows <= qt*32+31
    int qg = qt * 32 + wave * 16;
    size_t qrowbase = (size_t)(b * SEQ) + qg;

    bf16x8 aq[2];
#pragma unroll
    for (int kc = 0; kc < 2; ++kc)
        aq[kc] = *reinterpret_cast<const bf16x8*>(
            &Qb[(qrowbase + lr) * DHEAD + kc * 32 + g * 8]);

    // staging sources (pre-swizzled)
    const unsigned short* ksrc[4];
    const unsigned short* vsrc[4];
#pragma unroll
    for (int j = 0; j < 4; ++j) {
        int ci = wave * 256 + j * 64 + lane;
        int row = ci >> 3, c = ci & 7, cg = c ^ (row & 7);
        ksrc[j] = Kb + ((size_t)(b * SEQ) + row) * DHEAD + cg * 8;   // +t*64*DHEAD
        vsrc[j] = Vt + ((size_t)(b * DHEAD) + row) * SEQ + cg * 8;   // +t*64
    }

    float m_run[4], l_run[4];
    f32x4 of[4];
#pragma unroll
    for (int r = 0; r < 4; ++r) { m_run[r] = -1e30f; l_run[r] = 0.f; }
#pragma unroll
    for (int f = 0; f < 4; ++f) of[f] = (f32x4){0.f, 0.f, 0.f, 0.f};

    // prologue: stage tile 0 into buf 0
#pragma unroll
    for (int j = 0; j < 4; ++j) GLL16(ksrc[j], smem + wave * 4096 + j * 1024);
#pragma unroll
    for (int j = 0; j < 4; ++j) GLL16(vsrc[j], smem + 16384 + wave * 4096 + j * 1024);

    for (int t = 0; t < nt; ++t) {
        int cur = t & 1;
        if (t + 1 < nt) {
            int nb = cur ^ 1;
#pragma unroll
            for (int j = 0; j < 4; ++j)
                GLL16(ksrc[j] + (size_t)(t + 1) * 64 * DHEAD,
                      smem + nb * 8192 + wave * 4096 + j * 1024);
#pragma unroll
            for (int j = 0; j < 4; ++j)
                GLL16(vsrc[j] + (t + 1) * 64,
                      smem + 16384 + nb * 8192 + wave * 4096 + j * 1024);
            asm volatile("s_waitcnt vmcnt(8)" ::: "memory");
        } else {
            asm volatile("s_waitcnt vmcnt(0)" ::: "memory");
        }
        __builtin_amdgcn_s_barrier();
        asm volatile("" ::: "memory");

        const unsigned short* Kl = (const unsigned short*)(smem + cur * 8192);
        const unsigned short* Vl = (const unsigned short*)(smem + 16384 + cur * 8192);
        unsigned short* Pl = (unsigned short*)(smem + 32768) + wave * 1024;
        int kvb = t * 64;

        // S = Q K^T
        f32x4 s[4];
#pragma unroll
        for (int f = 0; f < 4; ++f) s[f] = (f32x4){0.f, 0.f, 0.f, 0.f};
#pragma unroll
        for (int kc = 0; kc < 2; ++kc) {
#pragma unroll
            for (int f = 0; f < 4; ++f) {
                int brow = f * 16 + lr;
                int cb = (kc * 4 + g) ^ (lr & 7);
                bf16x8 bk = *(const bf16x8*)&Kl[brow * 64 + cb * 8];
                s[f] = MFMA16(aq[kc], bk, s[f]);
            }
        }
        // scale + causal mask
#pragma unroll
        for (int f = 0; f < 4; ++f) {
            int kvg = kvb + f * 16 + lr;
#pragma unroll
            for (int r = 0; r < 4; ++r) {
                float sv = s[f][r] * ATT_SCALE;
                int qr = qg + g * 4 + r;
                s[f][r] = (kvg > qr) ? -1e30f : sv;
            }
        }
        // online softmax
#pragma unroll
        for (int r = 0; r < 4; ++r) {
            float mx = fmaxf(fmaxf(s[0][r], s[1][r]), fmaxf(s[2][r], s[3][r]));
            mx = fmaxf(mx, __shfl_xor(mx, 1));
            mx = fmaxf(mx, __shfl_xor(mx, 2));
            mx = fmaxf(mx, __shfl_xor(mx, 4));
            mx = fmaxf(mx, __shfl_xor(mx, 8));
            float nm = fmaxf(m_run[r], mx);
            float corr = __expf(m_run[r] - nm);
            m_run[r] = nm;
            float rs = 0.f;
#pragma unroll
            for (int f = 0; f < 4; ++f) {
                float p = __expf(s[f][r] - nm);
                s[f][r] = p;
                rs += p;
            }
            rs += __shfl_xor(rs, 1); rs += __shfl_xor(rs, 2);
            rs += __shfl_xor(rs, 4); rs += __shfl_xor(rs, 8);
            l_run[r] = l_run[r] * corr + rs;
#pragma unroll
            for (int fd = 0; fd < 4; ++fd) of[fd][r] *= corr;
        }
        // P -> per-wave LDS (swizzled), bf16
#pragma unroll
        for (int f = 0; f < 4; ++f) {
#pragma unroll
            for (int r = 0; r < 4; ++r) {
                int row = g * 4 + r, col = f * 16 + lr;
                int ch = (col >> 3) ^ (row & 7);
                Pl[row * 64 + ch * 8 + (col & 7)] = f2bf(s[f][r]);
            }
        }
        // O += P V
#pragma unroll
        for (int kc = 0; kc < 2; ++kc) {
            int cp = (kc * 4 + g) ^ (lr & 7);
            bf16x8 ap = *(const bf16x8*)&Pl[lr * 64 + cp * 8];
#pragma unroll
            for (int fd = 0; fd < 4; ++fd) {
                int vrow = fd * 16 + lr;
                int cv = (kc * 4 + g) ^ (lr & 7);
                bf16x8 bv = *(const bf16x8*)&Vl[vrow * 64 + cv * 8];
                of[fd] = MFMA16(ap, bv, of[fd]);
            }
        }
        asm volatile("" ::: "memory");
        __builtin_amdgcn_s_barrier();
    }
    // epilogue: normalize, store O bf16
#pragma unroll
    for (int fd = 0; fd < 4; ++fd) {
#pragma unroll
        for (int r = 0; r < 4; ++r) {
            Ob[(qrowbase + g * 4 + r) * DHEAD + fd * 16 + lr] =
                f2bf(of[fd][r] / l_run[r]);
        }
    }
}

// ---------------- kernel C: output projection ----------------
// Ob [16384][64] bf16 * Wob[1024][64] bf16 -> out [16384][1024] fp32
__global__ __launch_bounds__(256) void k_oproj(
    const unsigned short* __restrict__ Ob,
    const unsigned short* __restrict__ Wob,
    float* __restrict__ out)
{
    __shared__ __align__(16) unsigned short Wl[256 * 64];
    int tid = threadIdx.x;
    int wave = tid >> 6, lane = tid & 63, g = lane >> 4, lr = lane & 15;
    int mb = blockIdx.x * 64, nb = blockIdx.y * 256;

#pragma unroll
    for (int p = 0; p < 8; ++p) {
        int idx = p * 256 + tid;
        int row = idx >> 3, c = idx & 7;
        int ch = c ^ (row & 7);
        u32x4 v = *reinterpret_cast<const u32x4*>(
            &Wob[(size_t)(nb + row) * DHEAD + c * 8]);
        *reinterpret_cast<u32x4*>(&Wl[row * 64 + ch * 8]) = v;
    }
    __syncthreads();

    bf16x8 ao[2];
#pragma unroll
    for (int kc = 0; kc < 2; ++kc)
        ao[kc] = *reinterpret_cast<const bf16x8*>(
            &Ob[(size_t)(mb + wave * 16 + lr) * DHEAD + kc * 32 + g * 8]);

    f32x4 acc[16];
#pragma unroll
    for (int f = 0; f < 16; ++f) acc[f] = (f32x4){0.f, 0.f, 0.f, 0.f};
#pragma unroll
    for (int kc = 0; kc < 2; ++kc) {
#pragma unroll
        for (int f = 0; f < 16; ++f) {
            int brow = f * 16 + lr;
            int cb = (kc * 4 + g) ^ (brow & 7);
            bf16x8 bw = *reinterpret_cast<const bf16x8*>(&Wl[brow * 64 + cb * 8]);
            acc[f] = MFMA16(ao[kc], bw, acc[f]);
        }
    }
    int mrow = mb + wave * 16 + g * 4;
#pragma unroll
    for (int f = 0; f < 16; ++f) {
#pragma unroll
        for (int r = 0; r < 4; ++r)
            out[(size_t)(mrow + r) * DMODEL + nb + f * 16 + lr] = acc[f][r];
    }
}

extern "C" void kernel_launch(void* const* d_in, const int* in_sizes, int n_in,
                              void* d_out, int out_size, void* d_ws, size_t ws_size,
                              hipStream_t stream) {
    const float* x  = (const float*)d_in[0];
    const float* Wq = (const float*)d_in[1];
    const float* Wk = (const float*)d_in[2];
    const float* Wv = (const float*)d_in[3];
    const float* Wo = (const float*)d_in[4];
    float* out = (float*)d_out;

    unsigned short* Wb  = (unsigned short*)d_ws;   // 192*1024
    unsigned short* Wob = Wb + 196608;             // 1024*64
    unsigned short* Qb  = Wob + 65536;             // 16384*64
    unsigned short* Kb  = Qb + 1048576;
    unsigned short* Vt  = Kb + 1048576;            // [8][64][2048]
    unsigned short* Ob  = Vt + 1048576;

    k_cvt<<<256, 256, 0, stream>>>(Wq, Wk, Wv, Wo, Wb, Wob);
    k_qkv<<<256, 256, 0, stream>>>(x, Wb, Qb, Kb, Vt);
    k_attn<<<dim3(64, 8), 128, 0, stream>>>(Qb, Kb, Vt, Ob);
    k_oproj<<<dim3(256, 4), 256, 0, stream>>>(Ob, Wob, out);
}

// Round 3
// 68.050 us; speedup vs baseline: 2.0762x; 1.5104x over previous
//
#include <hip/hip_runtime.h>

#define SEQ 2048
#define DMODEL 1024
#define DHEAD 64
#define NROWS 16384
#define ATT_SCALE 0.03125f   // 1/sqrt(1024)

typedef __attribute__((ext_vector_type(8))) short bf16x8;
typedef __attribute__((ext_vector_type(4))) float f32x4;
typedef __attribute__((ext_vector_type(4))) unsigned int u32x4;
typedef __attribute__((ext_vector_type(4))) unsigned short u16x4;
typedef __attribute__((ext_vector_type(4))) float fl4;

#define MFMA16(a,b,c) __builtin_amdgcn_mfma_f32_16x16x32_bf16((a),(b),(c),0,0,0)
#define GLL16(g, l) __builtin_amdgcn_global_load_lds( \
    (const __attribute__((address_space(1))) void*)(g), \
    (__attribute__((address_space(3))) void*)(l), 16, 0, 0)

__device__ __forceinline__ unsigned short f2bf(float f) {
    union { float f; unsigned int u; } v; v.f = f;
    unsigned int u = v.u;
    unsigned int r = u + 0x7fffu + ((u >> 16) & 1u);
    return (unsigned short)(r >> 16);
}

// ---------------- kernel 0: convert weights to bf16 ----------------
__global__ __launch_bounds__(256) void k_cvt(
    const float* __restrict__ Wq, const float* __restrict__ Wk,
    const float* __restrict__ Wv, const float* __restrict__ Wo,
    unsigned short* __restrict__ Wb,    // [192][1024] (Wq;Wk;Wv)
    unsigned short* __restrict__ Wob)   // [1024][64]
{
    int i4 = blockIdx.x * 256 + threadIdx.x;
    const int W1 = 16384;
    const float* src; unsigned short* dst; int off;
    if (i4 < 3 * W1) {
        int which = i4 / W1;
        off = i4 - which * W1;
        src = (which == 0) ? Wq : (which == 1) ? Wk : Wv;
        dst = Wb + (size_t)which * 65536;
    } else {
        off = i4 - 3 * W1; src = Wo; dst = Wob;
    }
    fl4 v = reinterpret_cast<const fl4*>(src)[off];
    u16x4 o;
    o[0] = f2bf(v[0]); o[1] = f2bf(v[1]); o[2] = f2bf(v[2]); o[3] = f2bf(v[3]);
    reinterpret_cast<u16x4*>(dst)[off] = o;
}

// ---------------- kernel A: QKV projection, async pipelined ----------------
__global__ __launch_bounds__(256) void k_qkv(
    const float* __restrict__ x,
    const unsigned short* __restrict__ Wb,
    unsigned short* __restrict__ Qb,
    unsigned short* __restrict__ Kb,
    unsigned short* __restrict__ Vt)
{
    __shared__ __align__(16) char smem[81920];

    int tid = threadIdx.x;
    int wave = tid >> 6, lane = tid & 63, g = lane >> 4, lr = lane & 15;
    int mbase = blockIdx.x * 64;

    const float* xsrc[4];
#pragma unroll
    for (int j = 0; j < 4; ++j) {
        int ci = (wave * 4 + j) * 64 + lane;
        int row = ci >> 4, c = ci & 15, cg = c ^ (row & 7);
        xsrc[j] = x + (size_t)(mbase + row) * DMODEL + cg * 4;
    }
    const unsigned short* wsrc[6];
#pragma unroll
    for (int j = 0; j < 6; ++j) {
        int ci = (wave * 6 + j) * 64 + lane;
        int row = ci >> 3, c = ci & 7, cg = c ^ (row & 7);
        wsrc[j] = Wb + (size_t)row * DMODEL + cg * 8;
    }

    f32x4 acc[12];
#pragma unroll
    for (int f = 0; f < 12; ++f) acc[f] = (f32x4){0.f, 0.f, 0.f, 0.f};

#pragma unroll
    for (int j = 0; j < 4; ++j) GLL16(xsrc[j], smem + (wave * 4 + j) * 1024);
#pragma unroll
    for (int j = 0; j < 6; ++j) GLL16(wsrc[j], smem + 32768 + (wave * 6 + j) * 1024);

    for (int ks = 0; ks < 16; ++ks) {
        int cur = ks & 1;
        if (ks < 15) {
            int nb = cur ^ 1;
#pragma unroll
            for (int j = 0; j < 4; ++j)
                GLL16(xsrc[j] + (ks + 1) * 64, smem + nb * 16384 + (wave * 4 + j) * 1024);
#pragma unroll
            for (int j = 0; j < 6; ++j)
                GLL16(wsrc[j] + (ks + 1) * 64, smem + 32768 + nb * 24576 + (wave * 6 + j) * 1024);
            asm volatile("s_waitcnt vmcnt(10)" ::: "memory");
        } else {
            asm volatile("s_waitcnt vmcnt(0)" ::: "memory");
        }
        __builtin_amdgcn_s_barrier();
        asm volatile("" ::: "memory");

        const float* Xf = (const float*)(smem + cur * 16384);
        const unsigned short* Wf = (const unsigned short*)(smem + 32768 + cur * 24576);
        int arow = wave * 16 + lr;
#pragma unroll
        for (int kc = 0; kc < 2; ++kc) {
            int c0 = (kc * 8 + g * 2) ^ (lr & 7);
            int c1 = (kc * 8 + g * 2 + 1) ^ (lr & 7);
            fl4 xa = *(const fl4*)&Xf[arow * 64 + c0 * 4];
            fl4 xb = *(const fl4*)&Xf[arow * 64 + c1 * 4];
            bf16x8 a;
            a[0] = (short)f2bf(xa[0]); a[1] = (short)f2bf(xa[1]);
            a[2] = (short)f2bf(xa[2]); a[3] = (short)f2bf(xa[3]);
            a[4] = (short)f2bf(xb[0]); a[5] = (short)f2bf(xb[1]);
            a[6] = (short)f2bf(xb[2]); a[7] = (short)f2bf(xb[3]);
            __builtin_amdgcn_s_setprio(1);
#pragma unroll
            for (int f = 0; f < 12; ++f) {
                int brow = f * 16 + lr;
                int cb = (kc * 4 + g) ^ (lr & 7);
                bf16x8 b = *(const bf16x8*)&Wf[brow * 64 + cb * 8];
                acc[f] = MFMA16(a, b, acc[f]);
            }
            __builtin_amdgcn_s_setprio(0);
        }
        asm volatile("" ::: "memory");
        __builtin_amdgcn_s_barrier();
    }

    int mrow = mbase + wave * 16 + g * 4;
#pragma unroll
    for (int f = 0; f < 8; ++f) {
        int col = f * 16 + lr;
#pragma unroll
        for (int r = 0; r < 4; ++r) {
            unsigned short bv = f2bf(acc[f][r]);
            if (f < 4) Qb[(size_t)(mrow + r) * DHEAD + col] = bv;
            else       Kb[(size_t)(mrow + r) * DHEAD + col - 64] = bv;
        }
    }
    unsigned short* tmp = (unsigned short*)smem;  // [64][72]
#pragma unroll
    for (int f = 8; f < 12; ++f) {
        int h = (f - 8) * 16 + lr;
#pragma unroll
        for (int r = 0; r < 4; ++r)
            tmp[(wave * 16 + g * 4 + r) * 72 + h] = f2bf(acc[f][r]);
    }
    __syncthreads();
    int b = mbase >> 11, sbase = mbase & 2047;
    int h = tid >> 2, sc = tid & 3;
    u32x4 o0, o1;
#pragma unroll
    for (int j = 0; j < 4; ++j) {
        o0[j] = (unsigned int)tmp[(sc * 16 + 2 * j) * 72 + h] |
                ((unsigned int)tmp[(sc * 16 + 2 * j + 1) * 72 + h] << 16);
        o1[j] = (unsigned int)tmp[(sc * 16 + 8 + 2 * j) * 72 + h] |
                ((unsigned int)tmp[(sc * 16 + 9 + 2 * j) * 72 + h] << 16);
    }
    size_t off = ((size_t)(b * 64 + h)) * SEQ + sbase + sc * 16;
    *reinterpret_cast<u32x4*>(&Vt[off]) = o0;
    *reinterpret_cast<u32x4*>(&Vt[off + 8]) = o1;
}

// ---------------- kernel B: causal flash attention, kv-split, fixed-max ----
// Grid: 1024 blocks (qt heavy-first; per qt: 8 batches x 2 kv-parity-chunks).
// Block = 128 thr (2 waves x 16 q-rows). Softmax: fixed max m=0, per-lane
// deferred l-partials (no per-tile cross-lane ops). Outputs UNNORMALIZED
// O-partials (f32) + l-partials; combine happens in k_oproj.
__global__ __launch_bounds__(128) void k_attn(
    const unsigned short* __restrict__ Qb,
    const unsigned short* __restrict__ Kb,
    const unsigned short* __restrict__ Vt,
    float* __restrict__ Op,    // [2][16384][64]
    float* __restrict__ Lp)    // [2][16384]
{
    __shared__ __align__(16) char smem[36864];

    int tid = threadIdx.x;
    int wave = tid >> 6, lane = tid & 63, g = lane >> 4, lr = lane & 15;
    int bid = blockIdx.x;
    int qt = 63 - (bid >> 4);          // heavy q-tiles dispatched first
    int sub = bid & 15;
    int b = sub >> 1, chunk = sub & 1;
    int nt = qt / 2 + 1;               // kv tiles of 64 covering rows <= qt*32+31
    int my_nt = (nt + 1 - chunk) >> 1; // this chunk: tiles t = chunk, chunk+2, ...
    int qg = qt * 32 + wave * 16;
    size_t qrowbase = (size_t)(b * SEQ) + qg;

    bf16x8 aq[2];
#pragma unroll
    for (int kc = 0; kc < 2; ++kc)
        aq[kc] = *reinterpret_cast<const bf16x8*>(
            &Qb[(qrowbase + lr) * DHEAD + kc * 32 + g * 8]);

    const unsigned short* ksrc[4];
    const unsigned short* vsrc[4];
#pragma unroll
    for (int j = 0; j < 4; ++j) {
        int ci = wave * 256 + j * 64 + lane;
        int row = ci >> 3, c = ci & 7, cg = c ^ (row & 7);
        ksrc[j] = Kb + ((size_t)(b * SEQ) + row) * DHEAD + cg * 8;
        vsrc[j] = Vt + ((size_t)(b * DHEAD) + row) * SEQ + cg * 8;
    }

    float l_part[4];
    f32x4 of[4];
#pragma unroll
    for (int r = 0; r < 4; ++r) l_part[r] = 0.f;
#pragma unroll
    for (int f = 0; f < 4; ++f) of[f] = (f32x4){0.f, 0.f, 0.f, 0.f};

    if (my_nt > 0) {
        // prologue: stage first tile (t = chunk) into buf 0
#pragma unroll
        for (int j = 0; j < 4; ++j)
            GLL16(ksrc[j] + (size_t)chunk * 64 * DHEAD, smem + wave * 4096 + j * 1024);
#pragma unroll
        for (int j = 0; j < 4; ++j)
            GLL16(vsrc[j] + chunk * 64, smem + 16384 + wave * 4096 + j * 1024);

        for (int i = 0; i < my_nt; ++i) {
            int t = chunk + 2 * i;
            int cur = i & 1;
            if (i + 1 < my_nt) {
                int nb = cur ^ 1;
#pragma unroll
                for (int j = 0; j < 4; ++j)
                    GLL16(ksrc[j] + (size_t)(t + 2) * 64 * DHEAD,
                          smem + nb * 8192 + wave * 4096 + j * 1024);
#pragma unroll
                for (int j = 0; j < 4; ++j)
                    GLL16(vsrc[j] + (t + 2) * 64,
                          smem + 16384 + nb * 8192 + wave * 4096 + j * 1024);
                asm volatile("s_waitcnt vmcnt(8)" ::: "memory");
            } else {
                asm volatile("s_waitcnt vmcnt(0)" ::: "memory");
            }
            __builtin_amdgcn_s_barrier();
            asm volatile("" ::: "memory");

            const unsigned short* Kl = (const unsigned short*)(smem + cur * 8192);
            const unsigned short* Vl = (const unsigned short*)(smem + 16384 + cur * 8192);
            unsigned short* Pl = (unsigned short*)(smem + 32768) + wave * 1024;
            int kvb = t * 64;

            // S = Q K^T
            f32x4 s[4];
#pragma unroll
            for (int f = 0; f < 4; ++f) s[f] = (f32x4){0.f, 0.f, 0.f, 0.f};
            __builtin_amdgcn_s_setprio(1);
#pragma unroll
            for (int kc = 0; kc < 2; ++kc) {
#pragma unroll
                for (int f = 0; f < 4; ++f) {
                    int brow = f * 16 + lr;
                    int cb = (kc * 4 + g) ^ (lr & 7);
                    bf16x8 bk = *(const bf16x8*)&Kl[brow * 64 + cb * 8];
                    s[f] = MFMA16(aq[kc], bk, s[f]);
                }
            }
            __builtin_amdgcn_s_setprio(0);

            // scale + causal mask + exp (fixed max = 0) + per-lane l partial
#pragma unroll
            for (int f = 0; f < 4; ++f) {
                int kvg = kvb + f * 16 + lr;
#pragma unroll
                for (int r = 0; r < 4; ++r) {
                    int qr = qg + g * 4 + r;
                    float p = (kvg > qr) ? 0.f : __expf(s[f][r] * ATT_SCALE);
                    s[f][r] = p;
                    l_part[r] += p;
                }
            }
            // P -> per-wave LDS (swizzled), bf16
#pragma unroll
            for (int f = 0; f < 4; ++f) {
#pragma unroll
                for (int r = 0; r < 4; ++r) {
                    int row = g * 4 + r, col = f * 16 + lr;
                    int ch = (col >> 3) ^ (row & 7);
                    Pl[row * 64 + ch * 8 + (col & 7)] = f2bf(s[f][r]);
                }
            }
            // O += P V
#pragma unroll
            for (int kc = 0; kc < 2; ++kc) {
                int cp = (kc * 4 + g) ^ (lr & 7);
                bf16x8 ap = *(const bf16x8*)&Pl[lr * 64 + cp * 8];
                __builtin_amdgcn_s_setprio(1);
#pragma unroll
                for (int fd = 0; fd < 4; ++fd) {
                    int vrow = fd * 16 + lr;
                    int cv = (kc * 4 + g) ^ (lr & 7);
                    bf16x8 bv = *(const bf16x8*)&Vl[vrow * 64 + cv * 8];
                    of[fd] = MFMA16(ap, bv, of[fd]);
                }
                __builtin_amdgcn_s_setprio(0);
            }
            asm volatile("" ::: "memory");
            __builtin_amdgcn_s_barrier();
        }
    }

    // epilogue: reduce l across the 16-lane group (once), store partials
    float* opb = Op + ((size_t)chunk * NROWS + qrowbase) * 64;
#pragma unroll
    for (int r = 0; r < 4; ++r) {
        float ls = l_part[r];
        ls += __shfl_xor(ls, 1); ls += __shfl_xor(ls, 2);
        ls += __shfl_xor(ls, 4); ls += __shfl_xor(ls, 8);
        if (lr == 0)
            Lp[(size_t)chunk * NROWS + qrowbase + g * 4 + r] = ls;
#pragma unroll
        for (int fd = 0; fd < 4; ++fd)
            opb[(g * 4 + r) * 64 + fd * 16 + lr] = of[fd][r];
    }
}

// ---------------- kernel C: combine partials + output projection -----------
// O = (O0+O1)/(l0+l1) [16384][64] -> bf16 frag; out = O * Wob^T -> fp32
__global__ __launch_bounds__(256) void k_oproj(
    const float* __restrict__ Op,
    const float* __restrict__ Lp,
    const unsigned short* __restrict__ Wob,
    float* __restrict__ out)
{
    __shared__ __align__(16) unsigned short Wl[256 * 64];
    int tid = threadIdx.x;
    int wave = tid >> 6, lane = tid & 63, g = lane >> 4, lr = lane & 15;
    int mb = blockIdx.x * 64, nb = blockIdx.y * 256;

#pragma unroll
    for (int p = 0; p < 8; ++p) {
        int idx = p * 256 + tid;
        int row = idx >> 3, c = idx & 7;
        int ch = c ^ (row & 7);
        u32x4 v = *reinterpret_cast<const u32x4*>(
            &Wob[(size_t)(nb + row) * DHEAD + c * 8]);
        *reinterpret_cast<u32x4*>(&Wl[row * 64 + ch * 8]) = v;
    }
    __syncthreads();

    int row = mb + wave * 16 + lr;
    float inv = 1.0f / (Lp[row] + Lp[NROWS + row]);
    bf16x8 ao[2];
#pragma unroll
    for (int kc = 0; kc < 2; ++kc) {
        const float* p0 = &Op[(size_t)row * 64 + kc * 32 + g * 8];
        const float* p1 = &Op[(size_t)(NROWS + row) * 64 + kc * 32 + g * 8];
        fl4 a0 = *(const fl4*)p0, b0 = *(const fl4*)(p0 + 4);
        fl4 a1 = *(const fl4*)p1, b1 = *(const fl4*)(p1 + 4);
#pragma unroll
        for (int j = 0; j < 4; ++j) {
            ao[kc][j]     = (short)f2bf((a0[j] + a1[j]) * inv);
            ao[kc][j + 4] = (short)f2bf((b0[j] + b1[j]) * inv);
        }
    }

    f32x4 acc[16];
#pragma unroll
    for (int f = 0; f < 16; ++f) acc[f] = (f32x4){0.f, 0.f, 0.f, 0.f};
#pragma unroll
    for (int kc = 0; kc < 2; ++kc) {
        __builtin_amdgcn_s_setprio(1);
#pragma unroll
        for (int f = 0; f < 16; ++f) {
            int brow = f * 16 + lr;
            int cb = (kc * 4 + g) ^ (brow & 7);
            bf16x8 bw = *reinterpret_cast<const bf16x8*>(&Wl[brow * 64 + cb * 8]);
            acc[f] = MFMA16(ao[kc], bw, acc[f]);
        }
        __builtin_amdgcn_s_setprio(0);
    }
    int mrow = mb + wave * 16 + g * 4;
#pragma unroll
    for (int f = 0; f < 16; ++f) {
#pragma unroll
        for (int r = 0; r < 4; ++r)
            out[(size_t)(mrow + r) * DMODEL + nb + f * 16 + lr] = acc[f][r];
    }
}

extern "C" void kernel_launch(void* const* d_in, const int* in_sizes, int n_in,
                              void* d_out, int out_size, void* d_ws, size_t ws_size,
                              hipStream_t stream) {
    const float* x  = (const float*)d_in[0];
    const float* Wq = (const float*)d_in[1];
    const float* Wk = (const float*)d_in[2];
    const float* Wv = (const float*)d_in[3];
    const float* Wo = (const float*)d_in[4];
    float* out = (float*)d_out;

    unsigned short* Wb  = (unsigned short*)d_ws;   // 192*1024
    unsigned short* Wob = Wb + 196608;             // 1024*64
    unsigned short* Qb  = Wob + 65536;             // 16384*64
    unsigned short* Kb  = Qb + 1048576;
    unsigned short* Vt  = Kb + 1048576;            // [8][64][2048]
    float* Op = (float*)(Vt + 1048576);            // [2][16384][64]
    float* Lp = Op + 2 * NROWS * 64;               // [2][16384]

    k_cvt<<<256, 256, 0, stream>>>(Wq, Wk, Wv, Wo, Wb, Wob);
    k_qkv<<<256, 256, 0, stream>>>(x, Wb, Qb, Kb, Vt);
    k_attn<<<1024, 128, 0, stream>>>(Qb, Kb, Vt, Op, Lp);
    k_oproj<<<dim3(256, 4), 256, 0, stream>>>(Op, Lp, Wob, out);
}

// Round 5
// 66.469 us; speedup vs baseline: 2.1256x; 1.0238x over previous
//
#include <hip/hip_runtime.h>

#define SEQ 2048
#define DMODEL 1024
#define DHEAD 64
#define NROWS 16384
#define ATT_SC2 0.0450842300667f   // (1/sqrt(1024)) * log2(e), for exp2f

typedef __attribute__((ext_vector_type(8))) short bf16x8;
typedef __attribute__((ext_vector_type(4))) float f32x4;
typedef __attribute__((ext_vector_type(4))) unsigned int u32x4;
typedef __attribute__((ext_vector_type(4))) unsigned short u16x4;
typedef __attribute__((ext_vector_type(4))) float fl4;

#define MFMA16(a,b,c) __builtin_amdgcn_mfma_f32_16x16x32_bf16((a),(b),(c),0,0,0)
#define GLL16(g, l) __builtin_amdgcn_global_load_lds( \
    (const __attribute__((address_space(1))) void*)(g), \
    (__attribute__((address_space(3))) void*)(l), 16, 0, 0)

__device__ __forceinline__ unsigned short f2bf(float f) {
    union { float f; unsigned int u; } v; v.f = f;
    unsigned int u = v.u;
    unsigned int r = u + 0x7fffu + ((u >> 16) & 1u);
    return (unsigned short)(r >> 16);
}

// packed f32x2 -> bf16x2 (RNE) — T12 primitive, no builtin on gfx950
__device__ __forceinline__ unsigned int cvtpk(float lo, float hi) {
    unsigned int d;
    asm volatile("v_cvt_pk_bf16_f32 %0, %1, %2" : "=v"(d) : "v"(lo), "v"(hi));
    return d;
}

// ---------------- kernel 0: convert weights to bf16 ----------------
__global__ __launch_bounds__(256) void k_cvt(
    const float* __restrict__ Wq, const float* __restrict__ Wk,
    const float* __restrict__ Wv, const float* __restrict__ Wo,
    unsigned short* __restrict__ Wb,    // [192][1024] (Wq;Wk;Wv)
    unsigned short* __restrict__ Wob)   // [1024][64]
{
    int i4 = blockIdx.x * 256 + threadIdx.x;
    const int W1 = 16384;
    const float* src; unsigned short* dst; int off;
    if (i4 < 3 * W1) {
        int which = i4 / W1;
        off = i4 - which * W1;
        src = (which == 0) ? Wq : (which == 1) ? Wk : Wv;
        dst = Wb + (size_t)which * 65536;
    } else {
        off = i4 - 3 * W1; src = Wo; dst = Wob;
    }
    fl4 v = reinterpret_cast<const fl4*>(src)[off];
    u16x4 o;
    o[0] = f2bf(v[0]); o[1] = f2bf(v[1]); o[2] = f2bf(v[2]); o[3] = f2bf(v[3]);
    reinterpret_cast<u16x4*>(dst)[off] = o;
}

// ---------------- kernel A: QKV projection, async pipelined ----------------
__global__ __launch_bounds__(256) void k_qkv(
    const float* __restrict__ x,
    const unsigned short* __restrict__ Wb,
    unsigned short* __restrict__ Qb,
    unsigned short* __restrict__ Kb,
    unsigned short* __restrict__ Vt)
{
    __shared__ __align__(16) char smem[81920];

    int tid = threadIdx.x;
    int wave = tid >> 6, lane = tid & 63, g = lane >> 4, lr = lane & 15;
    int mbase = blockIdx.x * 64;

    const float* xsrc[4];
#pragma unroll
    for (int j = 0; j < 4; ++j) {
        int ci = (wave * 4 + j) * 64 + lane;
        int row = ci >> 4, c = ci & 15, cg = c ^ (row & 7);
        xsrc[j] = x + (size_t)(mbase + row) * DMODEL + cg * 4;
    }
    const unsigned short* wsrc[6];
#pragma unroll
    for (int j = 0; j < 6; ++j) {
        int ci = (wave * 6 + j) * 64 + lane;
        int row = ci >> 3, c = ci & 7, cg = c ^ (row & 7);
        wsrc[j] = Wb + (size_t)row * DMODEL + cg * 8;
    }

    f32x4 acc[12];
#pragma unroll
    for (int f = 0; f < 12; ++f) acc[f] = (f32x4){0.f, 0.f, 0.f, 0.f};

#pragma unroll
    for (int j = 0; j < 4; ++j) GLL16(xsrc[j], smem + (wave * 4 + j) * 1024);
#pragma unroll
    for (int j = 0; j < 6; ++j) GLL16(wsrc[j], smem + 32768 + (wave * 6 + j) * 1024);

    for (int ks = 0; ks < 16; ++ks) {
        int cur = ks & 1;
        if (ks < 15) {
            int nb = cur ^ 1;
#pragma unroll
            for (int j = 0; j < 4; ++j)
                GLL16(xsrc[j] + (ks + 1) * 64, smem + nb * 16384 + (wave * 4 + j) * 1024);
#pragma unroll
            for (int j = 0; j < 6; ++j)
                GLL16(wsrc[j] + (ks + 1) * 64, smem + 32768 + nb * 24576 + (wave * 6 + j) * 1024);
            asm volatile("s_waitcnt vmcnt(10)" ::: "memory");
        } else {
            asm volatile("s_waitcnt vmcnt(0)" ::: "memory");
        }
        __builtin_amdgcn_s_barrier();
        asm volatile("" ::: "memory");

        const float* Xf = (const float*)(smem + cur * 16384);
        const unsigned short* Wf = (const unsigned short*)(smem + 32768 + cur * 24576);
        int arow = wave * 16 + lr;
#pragma unroll
        for (int kc = 0; kc < 2; ++kc) {
            int c0 = (kc * 8 + g * 2) ^ (lr & 7);
            int c1 = (kc * 8 + g * 2 + 1) ^ (lr & 7);
            fl4 xa = *(const fl4*)&Xf[arow * 64 + c0 * 4];
            fl4 xb = *(const fl4*)&Xf[arow * 64 + c1 * 4];
            union { unsigned int u[4]; bf16x8 v; } a;
            a.u[0] = cvtpk(xa[0], xa[1]); a.u[1] = cvtpk(xa[2], xa[3]);
            a.u[2] = cvtpk(xb[0], xb[1]); a.u[3] = cvtpk(xb[2], xb[3]);
            __builtin_amdgcn_s_setprio(1);
#pragma unroll
            for (int f = 0; f < 12; ++f) {
                int brow = f * 16 + lr;
                int cb = (kc * 4 + g) ^ (lr & 7);
                bf16x8 b = *(const bf16x8*)&Wf[brow * 64 + cb * 8];
                acc[f] = MFMA16(a.v, b, acc[f]);
            }
            __builtin_amdgcn_s_setprio(0);
        }
        asm volatile("" ::: "memory");
        __builtin_amdgcn_s_barrier();
    }

    int mrow = mbase + wave * 16 + g * 4;
#pragma unroll
    for (int f = 0; f < 8; ++f) {
        int col = f * 16 + lr;
#pragma unroll
        for (int r = 0; r < 4; ++r) {
            unsigned short bv = f2bf(acc[f][r]);
            if (f < 4) Qb[(size_t)(mrow + r) * DHEAD + col] = bv;
            else       Kb[(size_t)(mrow + r) * DHEAD + col - 64] = bv;
        }
    }
    unsigned short* tmp = (unsigned short*)smem;  // [64][72]
#pragma unroll
    for (int f = 8; f < 12; ++f) {
        int h = (f - 8) * 16 + lr;
#pragma unroll
        for (int r = 0; r < 4; ++r)
            tmp[(wave * 16 + g * 4 + r) * 72 + h] = f2bf(acc[f][r]);
    }
    __syncthreads();
    int b = mbase >> 11, sbase = mbase & 2047;
    int h = tid >> 2, sc = tid & 3;
    u32x4 o0, o1;
#pragma unroll
    for (int j = 0; j < 4; ++j) {
        o0[j] = (unsigned int)tmp[(sc * 16 + 2 * j) * 72 + h] |
                ((unsigned int)tmp[(sc * 16 + 2 * j + 1) * 72 + h] << 16);
        o1[j] = (unsigned int)tmp[(sc * 16 + 8 + 2 * j) * 72 + h] |
                ((unsigned int)tmp[(sc * 16 + 9 + 2 * j) * 72 + h] << 16);
    }
    size_t off = ((size_t)(b * 64 + h)) * SEQ + sbase + sc * 16;
    *reinterpret_cast<u32x4*>(&Vt[off]) = o0;
    *reinterpret_cast<u32x4*>(&Vt[off + 8]) = o1;
}

// ---------------- kernel B: causal flash attention ----------------
// QBLK=64 (4 waves x 16 q-rows), KVBLK=64, 2-way kv-parity split.
// Grid 512 = 32 q-tiles (heavy first) x 8 batches x 2 chunks.
// Fixed-max softmax (exp2), per-lane deferred l. Wave-uniform mask skip.
// LDS 40KB: K 2x8KB @0, V 2x8KB @16384, P 4x2KB @32768.
__global__ __launch_bounds__(256) void k_attn(
    const unsigned short* __restrict__ Qb,
    const unsigned short* __restrict__ Kb,
    const unsigned short* __restrict__ Vt,
    float* __restrict__ Op,    // [2][16384][64]
    float* __restrict__ Lp)    // [2][16384]
{
    __shared__ __align__(16) char smem[40960];

    int tid = threadIdx.x;
    int wave = tid >> 6, lane = tid & 63, g = lane >> 4, lr = lane & 15;
    int bid = blockIdx.x;
    int qt = 31 - (bid >> 4);          // heavy q-tiles dispatched first
    int sub = bid & 15;
    int b = sub >> 1, chunk = sub & 1;
    int nt = qt + 1;                   // kv tiles of 64 covering rows <= qt*64+63
    int my_nt = (nt + 1 - chunk) >> 1; // this chunk's tiles: t = chunk, chunk+2, ...
    int qw = qt * 64 + wave * 16;      // this wave's first q-row
    size_t qrowbase = (size_t)(b * SEQ) + qw;

    bf16x8 aq[2];
#pragma unroll
    for (int kc = 0; kc < 2; ++kc)
        aq[kc] = *reinterpret_cast<const bf16x8*>(
            &Qb[(qrowbase + lr) * DHEAD + kc * 32 + g * 8]);

    // staging sources (pre-swizzled); 256 thr x 16B x 2 = 8KB per operand
    const unsigned short* ksrc[2];
    const unsigned short* vsrc[2];
#pragma unroll
    for (int j = 0; j < 2; ++j) {
        int ci = j * 256 + tid;
        int row = ci >> 3, c = ci & 7, cg = c ^ (row & 7);
        ksrc[j] = Kb + ((size_t)(b * SEQ) + row) * DHEAD + cg * 8;
        vsrc[j] = Vt + ((size_t)(b * DHEAD) + row) * SEQ + cg * 8;
    }

    float l_part[4];
    f32x4 of[4];
#pragma unroll
    for (int r = 0; r < 4; ++r) l_part[r] = 0.f;
#pragma unroll
    for (int f = 0; f < 4; ++f) of[f] = (f32x4){0.f, 0.f, 0.f, 0.f};

    if (my_nt > 0) {
        // prologue: stage tile t=chunk into buf 0
#pragma unroll
        for (int j = 0; j < 2; ++j)
            GLL16(ksrc[j] + (size_t)chunk * 64 * DHEAD, smem + j * 4096 + wave * 1024);
#pragma unroll
        for (int j = 0; j < 2; ++j)
            GLL16(vsrc[j] + chunk * 64, smem + 16384 + j * 4096 + wave * 1024);

        for (int i = 0; i < my_nt; ++i) {
            int t = chunk + 2 * i;
            int cur = i & 1;
            int kvb = t * 64;
            if (i + 1 < my_nt) {
                int nb = cur ^ 1;
#pragma unroll
                for (int j = 0; j < 2; ++j)
                    GLL16(ksrc[j] + (size_t)(t + 2) * 64 * DHEAD,
                          smem + nb * 8192 + j * 4096 + wave * 1024);
#pragma unroll
                for (int j = 0; j < 2; ++j)
                    GLL16(vsrc[j] + (t + 2) * 64,
                          smem + 16384 + nb * 8192 + j * 4096 + wave * 1024);
                asm volatile("s_waitcnt vmcnt(4)" ::: "memory");
            } else {
                asm volatile("s_waitcnt vmcnt(0)" ::: "memory");
            }
            __builtin_amdgcn_s_barrier();
            asm volatile("" ::: "memory");

            if (kvb <= qw + 15) {   // wave-uniform: skip fully-masked tiles
                const unsigned short* Kl = (const unsigned short*)(smem + cur * 8192);
                const unsigned short* Vl = (const unsigned short*)(smem + 16384 + cur * 8192);
                unsigned short* Pl = (unsigned short*)(smem + 32768) + wave * 1024;

                // S = Q K^T
                f32x4 s[4];
#pragma unroll
                for (int f = 0; f < 4; ++f) s[f] = (f32x4){0.f, 0.f, 0.f, 0.f};
                __builtin_amdgcn_s_setprio(1);
#pragma unroll
                for (int kc = 0; kc < 2; ++kc) {
#pragma unroll
                    for (int f = 0; f < 4; ++f) {
                        int brow = f * 16 + lr;
                        int cb = (kc * 4 + g) ^ (lr & 7);
                        bf16x8 bk = *(const bf16x8*)&Kl[brow * 64 + cb * 8];
                        s[f] = MFMA16(aq[kc], bk, s[f]);
                    }
                }
                __builtin_amdgcn_s_setprio(0);

                if (kvb + 63 <= qw) {
                    // fully unmasked: no compare/select needed
#pragma unroll
                    for (int f = 0; f < 4; ++f)
#pragma unroll
                        for (int r = 0; r < 4; ++r) {
                            float p = exp2f(s[f][r] * ATT_SC2);
                            s[f][r] = p;
                            l_part[r] += p;
                        }
                } else {
                    // diagonal tile: causal mask
#pragma unroll
                    for (int f = 0; f < 4; ++f) {
                        int kvg = kvb + f * 16 + lr;
#pragma unroll
                        for (int r = 0; r < 4; ++r) {
                            int qr = qw + g * 4 + r;
                            float p = exp2f(s[f][r] * ATT_SC2);
                            p = (kvg > qr) ? 0.f : p;
                            s[f][r] = p;
                            l_part[r] += p;
                        }
                    }
                }
                // P -> per-wave LDS (swizzled), bf16
#pragma unroll
                for (int f = 0; f < 4; ++f) {
#pragma unroll
                    for (int r = 0; r < 4; ++r) {
                        int row = g * 4 + r, col = f * 16 + lr;
                        int ch = (col >> 3) ^ (row & 7);
                        Pl[row * 64 + ch * 8 + (col & 7)] = f2bf(s[f][r]);
                    }
                }
                // O += P V
#pragma unroll
                for (int kc = 0; kc < 2; ++kc) {
                    int cp = (kc * 4 + g) ^ (lr & 7);
                    bf16x8 ap = *(const bf16x8*)&Pl[lr * 64 + cp * 8];
                    __builtin_amdgcn_s_setprio(1);
#pragma unroll
                    for (int fd = 0; fd < 4; ++fd) {
                        int vrow = fd * 16 + lr;
                        int cv = (kc * 4 + g) ^ (lr & 7);
                        bf16x8 bv = *(const bf16x8*)&Vl[vrow * 64 + cv * 8];
                        of[fd] = MFMA16(ap, bv, of[fd]);
                    }
                    __builtin_amdgcn_s_setprio(0);
                }
            }
            asm volatile("" ::: "memory");
            __builtin_amdgcn_s_barrier();
        }
    }

    // epilogue: reduce l across the 16-lane group, store partials
    float* opb = Op + ((size_t)chunk * NROWS + qrowbase) * 64;
#pragma unroll
    for (int r = 0; r < 4; ++r) {
        float ls = l_part[r];
        ls += __shfl_xor(ls, 1); ls += __shfl_xor(ls, 2);
        ls += __shfl_xor(ls, 4); ls += __shfl_xor(ls, 8);
        if (lr == 0)
            Lp[(size_t)chunk * NROWS + qrowbase + g * 4 + r] = ls;
#pragma unroll
        for (int fd = 0; fd < 4; ++fd)
            opb[(g * 4 + r) * 64 + fd * 16 + lr] = of[fd][r];
    }
}

// ---------------- kernel C: combine partials + output projection -----------
__global__ __launch_bounds__(256) void k_oproj(
    const float* __restrict__ Op,
    const float* __restrict__ Lp,
    const unsigned short* __restrict__ Wob,
    float* __restrict__ out)
{
    __shared__ __align__(16) unsigned short Wl[256 * 64];
    int tid = threadIdx.x;
    int wave = tid >> 6, lane = tid & 63, g = lane >> 4, lr = lane & 15;
    int mb = blockIdx.x * 64, nb = blockIdx.y * 256;

#pragma unroll
    for (int p = 0; p < 8; ++p) {
        int idx = p * 256 + tid;
        int row = idx >> 3, c = idx & 7;
        int ch = c ^ (row & 7);
        u32x4 v = *reinterpret_cast<const u32x4*>(
            &Wob[(size_t)(nb + row) * DHEAD + c * 8]);
        *reinterpret_cast<u32x4*>(&Wl[row * 64 + ch * 8]) = v;
    }
    __syncthreads();

    int row = mb + wave * 16 + lr;
    float inv = 1.0f / (Lp[row] + Lp[NROWS + row]);
    bf16x8 ao[2];
#pragma unroll
    for (int kc = 0; kc < 2; ++kc) {
        const float* p0 = &Op[(size_t)row * 64 + kc * 32 + g * 8];
        const float* p1 = &Op[(size_t)(NROWS + row) * 64 + kc * 32 + g * 8];
        fl4 a0 = *(const fl4*)p0, b0 = *(const fl4*)(p0 + 4);
        fl4 a1 = *(const fl4*)p1, b1 = *(const fl4*)(p1 + 4);
        union { unsigned int u[4]; bf16x8 v; } a;
        a.u[0] = cvtpk((a0[0] + a1[0]) * inv, (a0[1] + a1[1]) * inv);
        a.u[1] = cvtpk((a0[2] + a1[2]) * inv, (a0[3] + a1[3]) * inv);
        a.u[2] = cvtpk((b0[0] + b1[0]) * inv, (b0[1] + b1[1]) * inv);
        a.u[3] = cvtpk((b0[2] + b1[2]) * inv, (b0[3] + b1[3]) * inv);
        ao[kc] = a.v;
    }

    f32x4 acc[16];
#pragma unroll
    for (int f = 0; f < 16; ++f) acc[f] = (f32x4){0.f, 0.f, 0.f, 0.f};
#pragma unroll
    for (int kc = 0; kc < 2; ++kc) {
        __builtin_amdgcn_s_setprio(1);
#pragma unroll
        for (int f = 0; f < 16; ++f) {
            int brow = f * 16 + lr;
            int cb = (kc * 4 + g) ^ (brow & 7);
            bf16x8 bw = *reinterpret_cast<const bf16x8*>(&Wl[brow * 64 + cb * 8]);
            acc[f] = MFMA16(ao[kc], bw, acc[f]);
        }
        __builtin_amdgcn_s_setprio(0);
    }
    int mrow = mb + wave * 16 + g * 4;
#pragma unroll
    for (int f = 0; f < 16; ++f) {
#pragma unroll
        for (int r = 0; r < 4; ++r)
            out[(size_t)(mrow + r) * DMODEL + nb + f * 16 + lr] = acc[f][r];
    }
}

extern "C" void kernel_launch(void* const* d_in, const int* in_sizes, int n_in,
                              void* d_out, int out_size, void* d_ws, size_t ws_size,
                              hipStream_t stream) {
    const float* x  = (const float*)d_in[0];
    const float* Wq = (const float*)d_in[1];
    const float* Wk = (const float*)d_in[2];
    const float* Wv = (const float*)d_in[3];
    const float* Wo = (const float*)d_in[4];
    float* out = (float*)d_out;

    unsigned short* Wb  = (unsigned short*)d_ws;   // 192*1024
    unsigned short* Wob = Wb + 196608;             // 1024*64
    unsigned short* Qb  = Wob + 65536;             // 16384*64
    unsigned short* Kb  = Qb + 1048576;
    unsigned short* Vt  = Kb + 1048576;            // [8][64][2048]
    float* Op = (float*)(Vt + 1048576);            // [2][16384][64]
    float* Lp = Op + 2 * NROWS * 64;               // [2][16384]

    k_cvt<<<256, 256, 0, stream>>>(Wq, Wk, Wv, Wo, Wb, Wob);
    k_qkv<<<256, 256, 0, stream>>>(x, Wb, Qb, Kb, Vt);
    k_attn<<<512, 256, 0, stream>>>(Qb, Kb, Vt, Op, Lp);
    k_oproj<<<dim3(256, 4), 256, 0, stream>>>(Op, Lp, Wob, out);
}